// Round 13
// baseline (5119.674 us; speedup 1.0000x reference)
//
#include <hip/hip_runtime.h>
#include <stdint.h>

#define BDIM 64
#define TDIM 512
#define EDIM 512
#define HDIM 512

typedef __attribute__((ext_vector_type(8))) short bf16x8;
typedef __attribute__((ext_vector_type(4))) float f32x4;
typedef __attribute__((ext_vector_type(4))) unsigned int u32x4;
typedef __attribute__((ext_vector_type(4))) unsigned short u16x4;
typedef unsigned long long u64t;

static __device__ __forceinline__ unsigned short f2bf(float f) {
  union { float f; uint32_t u; } c; c.f = f;
  uint32_t u = c.u;
  uint32_t r = u + 0x7fffu + ((u >> 16) & 1u);
  return (unsigned short)(r >> 16);
}
static __device__ __forceinline__ float bf2f(unsigned short s) {
  union { uint32_t u; float f; } c; c.u = ((uint32_t)s) << 16;
  return c.f;
}

// float -> OCP e4m3fn (RNE, saturate) — weight conversion only (proven R3)
static __device__ __forceinline__ unsigned char f2e4m3(float f) {
  uint32_t u = __float_as_uint(f);
  unsigned char s = (unsigned char)((u >> 31) << 7);
  float a = fabsf(f);
  if (a >= 448.f) return (unsigned char)(s | 0x7e);
  if (a < 0.015625f) {
    int q = (int)rintf(a * 512.f);
    if (q >= 8) return (unsigned char)(s | 0x08);
    return (unsigned char)(s | q);
  }
  int e; frexpf(a, &e);
  int E = e - 1;
  int q = (int)rintf(ldexpf(a, 3 - E));
  if (q == 16) { q = 8; E++; }
  int exp8 = E + 7;
  if (exp8 >= 16) return (unsigned char)(s | 0x7e);
  return (unsigned char)(s | (exp8 << 3) | (q & 7));
}

// swizzle for 1KB-row tiles (512 bf16 per row)
#define SWZ(row, byteInRow) ((((row)*1024) + (byteInRow)) ^ ((((row)&7))<<4))
// swizzle for 128B-row tiles (64 bf16 per row)
#define SWZA(row, byteInRow) ((((row)*128) + (byteInRow)) ^ ((((row)&7))<<4))
// fp8 shadow row stride (bytes) — R4's anti-conflict pad
#define H8S 528
// lgr row stride (bytes): 1040 = 16B-aligned, rows spread over banks (~2-way)
#define GRS 1040

// ---------------- small utility kernels ----------------

__global__ void sentinel_kern(float* out, int n) {
  for (int i = blockIdx.x * blockDim.x + threadIdx.x; i < n; i += gridDim.x * blockDim.x)
    out[i] = -12345.0f;
}

__global__ void conv_w(const float* __restrict__ Wz, const float* __restrict__ Wr,
                       const float* __restrict__ Wh,
                       unsigned short* __restrict__ Wxb, unsigned short* __restrict__ Whb,
                       unsigned char* __restrict__ Wr8) {
  int idx = blockIdx.x * 256 + threadIdx.x;
  if (idx >= 3 * 512 * 1024) return;
  int g = idx >> 19;
  int rem = idx & 524287;
  int j = rem >> 10, k = rem & 1023;
  const float* W = (g == 0) ? Wz : (g == 1) ? Wr : Wh;
  float v = W[(size_t)j * 1024 + k];
  unsigned short b = f2bf(v);
  if (k < 512) Wxb[((size_t)g * 512 + j) * 512 + k] = b;
  else {
    Whb[((size_t)g * 512 + j) * 512 + (k - 512)] = b;
    if (g == 1) Wr8[(size_t)j * 512 + (k - 512)] = f2e4m3(v * 16.f);
  }
}

__global__ void conv_x(const float* __restrict__ x, unsigned short* __restrict__ xb, int n4) {
  for (int i = blockIdx.x * blockDim.x + threadIdx.x; i < n4; i += gridDim.x * blockDim.x) {
    f32x4 v = ((const f32x4*)x)[i];
    u16x4 o;
    o[0] = f2bf(v[0]); o[1] = f2bf(v[1]); o[2] = f2bf(v[2]); o[3] = f2bf(v[3]);
    ((u16x4*)xb)[i] = o;
  }
}

__global__ void add_out(float* __restrict__ out, const float* __restrict__ Hb, int n4) {
  for (int i = blockIdx.x * blockDim.x + threadIdx.x; i < n4; i += gridDim.x * blockDim.x) {
    f32x4 a = ((const f32x4*)out)[i];
    f32x4 b = ((const f32x4*)Hb)[i];
    ((f32x4*)out)[i] = a + b;
  }
}

// ---------------- phase A: G = x @ Wx^T + bias (bf16 out) ----------------

__global__ __launch_bounds__(256, 2)
void gru_xproj(const unsigned short* __restrict__ xb,
               const unsigned short* __restrict__ Wxb,
               const float* __restrict__ bz, const float* __restrict__ br,
               const float* __restrict__ bh,
               unsigned short* __restrict__ Gb) {
  __shared__ __align__(16) unsigned short lA[128 * 64];
  __shared__ __align__(16) unsigned short lB[128 * 64];
  const int tid = threadIdx.x;
  const int m0 = blockIdx.x * 128;
  const int n0 = blockIdx.y * 128;
  const int w = tid >> 6, lane = tid & 63, cl = lane & 15, q = lane >> 4;
  const int wr = w >> 1, wc = w & 1;
  f32x4 acc[4][4];
#pragma unroll
  for (int i = 0; i < 4; i++)
#pragma unroll
    for (int j = 0; j < 4; j++) acc[i][j] = (f32x4){0.f, 0.f, 0.f, 0.f};

  for (int ko = 0; ko < 8; ko++) {
    int k0 = ko * 64;
#pragma unroll
    for (int cc = 0; cc < 4; cc++) {
      int qq = tid * 4 + cc;
      int row = qq >> 3, kc = qq & 7;
      u32x4 va = *(const u32x4*)(xb + ((size_t)(m0 + row) * EDIM + k0 + kc * 8));
      *(u32x4*)((char*)lA + SWZA(row, kc * 16)) = va;
      u32x4 vb = *(const u32x4*)(Wxb + ((size_t)(n0 + row) * EDIM + k0 + kc * 8));
      *(u32x4*)((char*)lB + SWZA(row, kc * 16)) = vb;
    }
    __syncthreads();
#pragma unroll
    for (int ks = 0; ks < 2; ks++) {
      bf16x8 af[4], bfv[4];
#pragma unroll
      for (int i = 0; i < 4; i++) {
        int rl = wr * 64 + i * 16 + cl;
        af[i] = *(const bf16x8*)((char*)lA + SWZA(rl, ks * 64 + q * 16));
      }
#pragma unroll
      for (int j = 0; j < 4; j++) {
        int rl = wc * 64 + j * 16 + cl;
        bfv[j] = *(const bf16x8*)((char*)lB + SWZA(rl, ks * 64 + q * 16));
      }
#pragma unroll
      for (int i = 0; i < 4; i++)
#pragma unroll
        for (int j = 0; j < 4; j++)
          acc[i][j] = __builtin_amdgcn_mfma_f32_16x16x32_bf16(af[i], bfv[j], acc[i][j], 0, 0, 0);
    }
    __syncthreads();
  }
  const int g = n0 >> 9;
  const float* bias = (g == 0) ? bz : (g == 1) ? br : bh;
#pragma unroll
  for (int i = 0; i < 4; i++) {
#pragma unroll
    for (int j = 0; j < 4; j++) {
      int n = n0 + wc * 64 + j * 16 + cl;
      float bv = bias[n & 511];
#pragma unroll
      for (int ii = 0; ii < 4; ii++) {
        int m = m0 + wr * 64 + i * 16 + q * 4 + ii;
        Gb[(size_t)m * 1536 + n] = f2bf(acc[i][j][ii] + bv);
      }
    }
  }
}

// ---------------- persistent recurrence: SINGLE exchange per step ----------
// 128 wgs: gid = bid&7 (dir=gid>>2, bg=gid&3); cg = bid>>3, own cols j0=cg*32.
// r-gate replicated per-wg (fp8 x16 Wr in VGPRs; wave w owns r-cols w*128..+127)
// so the mid-step r*h exchange is eliminated. Only h(t) is exchanged (parity
// double-buffered). Mechanics from the proven R12 kernel: per-wg 128B flag
// lines, coalesced staging, packed publishes, outp after flag.
// Wave roles: w0,1 = r(0..255) + h~ + blend/publish; w2,3 = r(256..511) + z.

__global__ __launch_bounds__(256, 1)
void gru_persist(const unsigned short* __restrict__ Gb,
                 const float* __restrict__ h0,
                 unsigned short* __restrict__ Hstb,   // [2][2*64][512] bf16
                 unsigned int*   __restrict__ flags,  // [8][16] x 128B lines
                 float* __restrict__ outp,
                 float* __restrict__ Hb,
                 const unsigned short* __restrict__ Whb,
                 const unsigned char*  __restrict__ Wr8) {
  __shared__ __align__(16) unsigned short lw_z[32 * 512];   // 32KB own-col z weights
  __shared__ __align__(16) unsigned short lw_h[32 * 512];   // 32KB own-col h~ weights
  __shared__ __align__(16) unsigned short lhb[16 * 512];    // 16KB staged h (SWZ)
  __shared__ __align__(16) unsigned short lrh[16 * 512];    // 16KB r*h (SWZ)
  __shared__ __align__(16) unsigned char  lgr[16 * GRS];    // 16.25KB G_r slice
  __shared__ __align__(16) unsigned char  lh8[16 * H8S];    // 8.25KB fp8 shadow
  __shared__ float lz[16 * 32];                              // 2KB z values
  __shared__ float lhp[16 * 32];                             // 2KB own-col h fp32

  const int tid = threadIdx.x;
  const int bid = blockIdx.x;
  const int gid = bid & 7;
  const int cg = bid >> 3;
  const int dir = gid >> 2;
  const int bg = gid & 3;
  const int j0 = cg * 32;
  const int w = tid >> 6;
  const int lane = tid & 63;
  const int c = lane & 15;
  const int q = lane >> 4;
  const int sub = w & 1;            // for w0,1: own col half
  const int jn = j0 + sub * 16 + c; // w0,1's blend/publish column
  const int rj0 = w * 128;          // this wave's replicated r columns
  const int HHALF = 2 * 64 * 512;

  unsigned int* fh_base = flags + gid * 16 * 32;
  unsigned int* fh_own  = fh_base + cg * 32;

  // ---- one-time: weight LDS tiles (z gate0, h~ gate2; own 32 cols) ----
  {
    int col = tid >> 3, ch = tid & 7;
#pragma unroll
    for (int u = 0; u < 8; u++) {
      u32x4 vz = *(const u32x4*)(Whb + (((size_t)0 * 512 + j0 + col) * 512) + ch * 64 + u * 8);
      *(u32x4*)((char*)lw_z + SWZ(col, ch * 128 + u * 16)) = vz;
      u32x4 vh = *(const u32x4*)(Whb + (((size_t)2 * 512 + j0 + col) * 512) + ch * 64 + u * 8);
      *(u32x4*)((char*)lw_h + SWZ(col, ch * 128 + u * 16)) = vh;
    }
  }
  // ---- one-time: Wr fp8 fragments into VGPRs (wave's 128 r-cols) ----
  u64t wrg[8][16];
  {
    const u64t* wsrc = (const u64t*)Wr8;
#pragma unroll
    for (int ct = 0; ct < 8; ct++)
#pragma unroll
      for (int ks = 0; ks < 16; ks++)
        wrg[ct][ks] = wsrc[(size_t)(rj0 + ct * 16 + c) * 64 + ks * 4 + q];
  }
  // ---- init own-col h (fp32) + publish h0 into parity-0 slab ----
  {
    int row = tid >> 4, jl2 = (tid & 15) * 2;
    int b = bg * 16 + row;
    float v0 = h0[(size_t)b * HDIM + j0 + jl2];
    float v1 = h0[(size_t)b * HDIM + j0 + jl2 + 1];
    lhp[row * 32 + jl2] = v0;
    lhp[row * 32 + jl2 + 1] = v1;
    unsigned int pk = (unsigned int)f2bf(v0) | ((unsigned int)f2bf(v1) << 16);
    __hip_atomic_store((unsigned int*)&Hstb[(size_t)(dir * 64 + b) * 512 + j0 + jl2], pk,
                       __ATOMIC_RELAXED, __HIP_MEMORY_SCOPE_AGENT);
  }
  asm volatile("s_waitcnt vmcnt(0)" ::: "memory");
  __syncthreads();
  if (tid == 0)
    __hip_atomic_store(fh_own, 1u, __ATOMIC_RELAXED, __HIP_MEMORY_SCOPE_AGENT);

  const float inv256 = 1.f / 256.f;

  for (int s = 1; s <= TDIM; s++) {
    int t = dir ? (TDIM - s) : (s - 1);
    const unsigned short* Hstb_r = Hstb + (size_t)((s - 1) & 1) * HHALF;
    unsigned short* Hstb_w = Hstb + (size_t)(s & 1) * HHALF;
    const unsigned tgt = (unsigned)s;

    // ---- pre-poll: stage G_r slice (all 512 cols x 16 batches) into lgr ----
    {
      int row = tid >> 4, seg = tid & 15;
      const unsigned short* src = Gb + ((size_t)(bg * 16 + row) * TDIM + t) * 1536 + 512 + seg * 32;
      u32x4 g0 = *(const u32x4*)(src);
      u32x4 g1 = *(const u32x4*)(src + 8);
      u32x4 g2 = *(const u32x4*)(src + 16);
      u32x4 g3 = *(const u32x4*)(src + 24);
      char* d = (char*)lgr + row * GRS + seg * 64;
      *(u32x4*)(d)      = g0;
      *(u32x4*)(d + 16) = g1;
      *(u32x4*)(d + 32) = g2;
      *(u32x4*)(d + 48) = g3;
    }
    // ---- pre-poll: per-role G prefetch into regs ----
    f32x4 gPre;   // w0,1: g_h for col jn ; w2,3: g_z for col j0+(w-2)*16+c
    {
      int gate = (w < 2) ? 2 : 0;
      int jcol = (w < 2) ? jn : (j0 + (w - 2) * 16 + c);
#pragma unroll
      for (int i = 0; i < 4; i++) {
        int b = bg * 16 + q * 4 + i;
        gPre[i] = bf2f(Gb[((size_t)b * TDIM + t) * 1536 + gate * 512 + jcol]);
      }
    }

    // ---- wait: h(s-1) published by all 16 wgs (per-wg lines, wave0 poll) ----
    if (w == 0) {
      while (true) {
        unsigned fv = tgt;
        if (lane < 16)
          fv = __hip_atomic_load(fh_base + lane * 32,
                                 __ATOMIC_RELAXED, __HIP_MEMORY_SCOPE_AGENT);
        if (__all(fv >= tgt)) break;
        __builtin_amdgcn_s_sleep(1);
      }
    }
    __syncthreads();

    // ---- stage h(s-1): coalesced atomic loads -> lhb (SWZ) + fp8 shadow ----
    {
      int row = tid >> 4, seg = tid & 15;
      const char* srcb = (const char*)Hstb_r +
                         (size_t)(dir * 64 + bg * 16 + row) * 1024 + seg * 8;
      u64t v[8];
#pragma unroll
      for (int i = 0; i < 8; i++)
        v[i] = __hip_atomic_load((const u64t*)(srcb + i * 128),
                                 __ATOMIC_RELAXED, __HIP_MEMORY_SCOPE_AGENT);
      char* dst = (char*)lhb;
#pragma unroll
      for (int i = 0; i < 8; i++)
        *(u64t*)(dst + SWZ(row, seg * 8 + i * 128)) = v[i];
      // fp8 shadow (x16 scale) via HW converter — proven R4 path
#pragma unroll
      for (int i = 0; i < 8; i++) {
        const unsigned short* sp = (const unsigned short*)&v[i];
        float f0 = bf2f(sp[0]) * 16.f, f1 = bf2f(sp[1]) * 16.f;
        float f2 = bf2f(sp[2]) * 16.f, f3 = bf2f(sp[3]) * 16.f;
        int d = 0;
        d = __builtin_amdgcn_cvt_pk_fp8_f32(f0, f1, d, false);
        d = __builtin_amdgcn_cvt_pk_fp8_f32(f2, f3, d, true);
        *(unsigned int*)(lh8 + row * H8S + i * 64 + seg * 4) = (unsigned int)d;
      }
    }
    __syncthreads();

    // ---- fp8 A-fragments from LDS shadow (proven R4 layout) ----
    u64t af8[16];
#pragma unroll
    for (int ks = 0; ks < 16; ks++)
      af8[ks] = *(const u64t*)(lh8 + c * H8S + ks * 32 + q * 8);

    // ---- r-matmul: 8 col-tiles x K=512, fp8, weights in VGPRs (all waves) ----
    f32x4 racc[8];
#pragma unroll
    for (int ct = 0; ct < 8; ct++) racc[ct] = (f32x4){0.f, 0.f, 0.f, 0.f};
#pragma unroll
    for (int ks = 0; ks < 16; ks++)
#pragma unroll
      for (int ct = 0; ct < 8; ct++)
        racc[ct] = __builtin_amdgcn_mfma_f32_16x16x32_fp8_fp8(
            (long)af8[ks], (long)wrg[ct][ks], racc[ct], 0, 0, 0);

    // ---- z-matmul (waves 2,3): bf16, own cols -> lz ----
    if (w >= 2) {
      int zs = w - 2;
      f32x4 zacc = (f32x4){0.f, 0.f, 0.f, 0.f};
#pragma unroll
      for (int ks = 0; ks < 16; ks++) {
        bf16x8 azf = *(const bf16x8*)((char*)lhb + SWZ(c, ks * 64 + q * 16));
        bf16x8 bzf = *(const bf16x8*)((char*)lw_z + SWZ(zs * 16 + c, ks * 64 + q * 16));
        zacc = __builtin_amdgcn_mfma_f32_16x16x32_bf16(azf, bzf, zacc, 0, 0, 0);
      }
#pragma unroll
      for (int i = 0; i < 4; i++) {
        int row = q * 4 + i, zl = zs * 16 + c;
        float pre = zacc[i] + gPre[i];
        pre = fminf(fmaxf(pre, -30.f), 30.f);
        lz[row * 32 + zl] = 1.f / (1.f + __expf(-pre));
      }
    }

    // ---- r pointwise + r*h into lrh (all waves, own 128 r-cols) ----
#pragma unroll
    for (int ct = 0; ct < 8; ct++) {
      int j = rj0 + ct * 16 + c;
#pragma unroll
      for (int i = 0; i < 4; i++) {
        int row = q * 4 + i;
        float gr = bf2f(*(const unsigned short*)(lgr + row * GRS + j * 2));
        float pre = racc[ct][i] * inv256 + gr;
        pre = fminf(fmaxf(pre, -30.f), 30.f);
        float r = 1.f / (1.f + __expf(-pre));
        float hb = bf2f(*(const unsigned short*)((char*)lhb + SWZ(row, j * 2)));
        *(unsigned short*)((char*)lrh + SWZ(row, j * 2)) = f2bf(r * hb);
      }
    }
    __syncthreads();   // lrh + lz ready

    // ---- h~ matmul + blend + publish (waves 0,1) ----
    float hn[4];
    if (w < 2) {
      f32x4 hacc = (f32x4){0.f, 0.f, 0.f, 0.f};
#pragma unroll
      for (int ks = 0; ks < 16; ks++) {
        bf16x8 arf = *(const bf16x8*)((char*)lrh + SWZ(c, ks * 64 + q * 16));
        bf16x8 bhf = *(const bf16x8*)((char*)lw_h + SWZ(sub * 16 + c, ks * 64 + q * 16));
        hacc = __builtin_amdgcn_mfma_f32_16x16x32_bf16(arf, bhf, hacc, 0, 0, 0);
      }
#pragma unroll
      for (int i = 0; i < 4; i++) {
        int row = q * 4 + i, hl = sub * 16 + c;
        float pre = hacc[i] + gPre[i];
        pre = fminf(fmaxf(pre, -15.f), 15.f);
        float e2 = __expf(2.f * pre);
        float th = (e2 - 1.f) / (e2 + 1.f);
        float hp = lhp[row * 32 + hl];
        float z = lz[row * 32 + hl];
        hn[i] = hp + z * (th - hp);
        lhp[row * 32 + hl] = hn[i];
      }
      // packed publish of h(s) into the parity slab
#pragma unroll
      for (int i = 0; i < 4; i++) {
        float oth = __shfl_xor(hn[i], 1);
        if (!(c & 1)) {
          int b = bg * 16 + q * 4 + i;
          unsigned int pk = (unsigned int)f2bf(hn[i]) | ((unsigned int)f2bf(oth) << 16);
          __hip_atomic_store(
              (unsigned int*)&Hstb_w[(size_t)(dir * 64 + b) * 512 + jn],
              pk, __ATOMIC_RELAXED, __HIP_MEMORY_SCOPE_AGENT);
        }
      }
    }
    asm volatile("s_waitcnt vmcnt(0)" ::: "memory");
    __syncthreads();
    if (tid == 0)
      __hip_atomic_store(fh_own, (unsigned)(s + 1), __ATOMIC_RELAXED, __HIP_MEMORY_SCOPE_AGENT);

    // ---- outp stores AFTER the flag (drain deferred into next poll) ----
    if (w < 2) {
      float* op = dir ? Hb : outp;
#pragma unroll
      for (int i = 0; i < 4; i++) {
        int b = bg * 16 + q * 4 + i;
        op[((size_t)b * TDIM + t) * HDIM + jn] = hn[i];
      }
    }
  }
}

// ---------------- host ----------------

extern "C" void kernel_launch(void* const* d_in, const int* in_sizes, int n_in,
                              void* d_out, int out_size, void* d_ws, size_t ws_size,
                              hipStream_t stream) {
  (void)in_sizes; (void)n_in;
  const float* x  = (const float*)d_in[0];
  const float* h0 = (const float*)d_in[1];
  const float* Wz = (const float*)d_in[2];
  const float* bz = (const float*)d_in[3];
  const float* Wr = (const float*)d_in[4];
  const float* br = (const float*)d_in[5];
  const float* Wh = (const float*)d_in[6];
  const float* bh = (const float*)d_in[7];
  float* outp = (float*)d_out;

  const size_t szG    = (size_t)32768 * 1536 * 2;       // bf16 G
  const size_t szXb   = (size_t)BDIM * TDIM * EDIM * 2;
  const size_t szW    = (size_t)3 * 512 * 512 * 2;
  const size_t szWr8  = (size_t)512 * 512;
  const size_t szHb   = (size_t)BDIM * TDIM * HDIM * 4;
  const size_t szHstb = (size_t)2 * 2 * 64 * 512 * 2;   // parity-double slab
  const size_t szFl   = 16384;                          // 8x16 x 128B lines
  const size_t fixed  = szXb + 2 * szW + szWr8 + szHb + szHstb + szFl + 16384;

  if (ws_size < fixed + szG) {
    sentinel_kern<<<256, 256, 0, stream>>>(outp, out_size);
    return;
  }

  size_t off = 0;
  char* base = (char*)d_ws;
  auto alloc = [&](size_t sz) { char* p = base + off; off = (off + sz + 255) & ~(size_t)255; return p; };
  unsigned short* Gb   = (unsigned short*)alloc(szG);
  unsigned short* xb   = (unsigned short*)alloc(szXb);
  unsigned short* Wxb  = (unsigned short*)alloc(szW);
  unsigned short* Whb  = (unsigned short*)alloc(szW);
  unsigned char*  Wr8  = (unsigned char*)alloc(szWr8);
  float*          Hbuf = (float*)alloc(szHb);
  unsigned short* Hstb = (unsigned short*)alloc(szHstb);
  unsigned int*   flags= (unsigned int*)alloc(szFl);

  hipMemsetAsync(flags, 0, szFl, stream);
  conv_w<<<(3 * 512 * 1024 + 255) / 256, 256, 0, stream>>>(Wz, Wr, Wh, Wxb, Whb, Wr8);
  conv_x<<<2048, 256, 0, stream>>>(x, xb, (BDIM * TDIM * EDIM) / 4);
  gru_xproj<<<dim3(256, 12), 256, 0, stream>>>(xb, Wxb, bz, br, bh, Gb);
  gru_persist<<<128, 256, 0, stream>>>(Gb, h0, Hstb, flags, outp, Hbuf, Whb, Wr8);
  add_out<<<2048, 256, 0, stream>>>(outp, Hbuf, (BDIM * TDIM * HDIM) / 4);
  hipMemcpyAsync(outp + (size_t)BDIM * TDIM * HDIM, h0,
                 (size_t)BDIM * HDIM * sizeof(float), hipMemcpyDeviceToDevice, stream);
}